// Round 1
// 5711.769 us; speedup vs baseline: 1.3748x; 1.3748x over previous
//
#include <hip/hip_runtime.h>
#include <cstdint>

#define SEQ   1024
#define BATCH 128
#define INP   128
#define HID   512
#define OUTP  64
#define M1    (SEQ*BATCH)          // 131072

#define OMA_F   0.8f               // 1 - alpha
#define AL_F    0.2f               // alpha
#define SIGMA_F 0.031622776601683794f  // sqrt(2*0.2)*0.05

#define NGROUP  32                 // batch groups (4 rows each)
#define NSLICE  8                  // j-slices per group (64 j each)

// ---------------------------------------------------------------------------
// Phase 1: proj[s,b,h] = sum_i x[s,b,i]*W_in[h,i] + b_in[h]
// (unchanged from previous round)
// ---------------------------------------------------------------------------
__global__ __launch_bounds__(256) void proj_gemm_kernel(
    const float* __restrict__ x, const float* __restrict__ W_in,
    const float* __restrict__ b_in, float* __restrict__ act)
{
    __shared__ __align__(16) float xs[64*68];
    __shared__ __align__(16) float ws[64*70];
    const int bid = blockIdx.x;
    const int mt = bid >> 3, nt = bid & 7;
    const int m0 = mt << 6, n0 = nt << 6;
    const int t  = threadIdx.x;
    const int tm = t >> 4, tn = t & 15;
    float acc[4][4] = {{0.f,0.f,0.f,0.f},{0.f,0.f,0.f,0.f},
                       {0.f,0.f,0.f,0.f},{0.f,0.f,0.f,0.f}};
    for (int kc = 0; kc < INP; kc += 64) {
        #pragma unroll
        for (int n = 0; n < 4; n++) {
            int f = n*256 + t;
            int row = f >> 4, c4 = (f & 15) << 2;
            float4 v = *(const float4*)&x[(size_t)(m0+row)*INP + kc + c4];
            *(float4*)&xs[row*68 + c4] = v;
        }
        #pragma unroll
        for (int n = 0; n < 4; n++) {
            int f = n*256 + t;
            int row = f >> 4, c4 = (f & 15) << 2;
            float4 v = *(const float4*)&W_in[(size_t)(n0+row)*INP + kc + c4];
            *(float2*)&ws[row*70 + c4]     = make_float2(v.x, v.y);
            *(float2*)&ws[row*70 + c4 + 2] = make_float2(v.z, v.w);
        }
        __syncthreads();
        #pragma unroll
        for (int k = 0; k < 64; k += 4) {
            float4 xv[4]; float4 wv[4];
            #pragma unroll
            for (int i = 0; i < 4; i++)
                xv[i] = *(const float4*)&xs[(tm*4+i)*68 + k];
            #pragma unroll
            for (int jj = 0; jj < 4; jj++) {
                float2 a = *(const float2*)&ws[(tn*4+jj)*70 + k];
                float2 b = *(const float2*)&ws[(tn*4+jj)*70 + k + 2];
                wv[jj] = make_float4(a.x, a.y, b.x, b.y);
            }
            #pragma unroll
            for (int i = 0; i < 4; i++)
                #pragma unroll
                for (int jj = 0; jj < 4; jj++)
                    acc[i][jj] += xv[i].x*wv[jj].x + xv[i].y*wv[jj].y
                                + xv[i].z*wv[jj].z + xv[i].w*wv[jj].w;
        }
        __syncthreads();
    }
    float4 bv = make_float4(b_in[n0+tn*4+0], b_in[n0+tn*4+1],
                            b_in[n0+tn*4+2], b_in[n0+tn*4+3]);
    #pragma unroll
    for (int i = 0; i < 4; i++) {
        float4 o = make_float4(acc[i][0]+bv.x, acc[i][1]+bv.y,
                               acc[i][2]+bv.z, acc[i][3]+bv.w);
        *(float4*)&act[(size_t)(m0+tm*4+i)*HID + n0 + tn*4] = o;
    }
}

// ---------------------------------------------------------------------------
// Phase 2: sequential scan.
// 256 blocks = 32 groups (4 batch rows) x 8 slices (64 hidden j's).
// Handshake v2:
//  - per-(parity, group, slice) sequence SLOTS (plain agent store of s+1)
//    replace the shared fetch_add counter: no same-address RMW serialization.
//    ABA-safe: producer can only overwrite its slot (at step s+2) after it
//    has observed every peer's (s+1)-slot, which requires every peer (i.e.
//    every poller of this slot) to have passed its s-poll.
//  - consumer polls all 8 slots with 8 lanes in parallel + __ballot: one
//    LLC round trip per poll round.
//  - act[] store moved AFTER the slot store: its commit latency drains
//    during the next step's spin instead of inside the pre-flag vmcnt(0).
//  - part[] relaid out as [r][q][j]: j-consecutive per wave on both the
//    write and the read side -> no LDS bank conflicts in the reduction.
// ---------------------------------------------------------------------------
__global__ __launch_bounds__(256, 1) void scan_kernel(
    const float* __restrict__ noise, const float* __restrict__ W_h,
    const float* __restrict__ b_h, float* __restrict__ act,
    float* h_buf, int* slots)
{
    __shared__ __align__(16) float h_lds[4*512];   // 4 rows x 512
    __shared__ __align__(16) float part[4*4*64];   // [r][q][j]
    const int bid = blockIdx.x;
    const int g  = bid & (NGROUP-1);      // group: rows b0..b0+3
    const int p  = bid >> 5;              // slice: j0..j0+63
    const int b0 = g << 2;
    const int j0 = p << 6;
    const int t  = threadIdx.x;
    const int j  = t & 63;
    const int q  = t >> 6;                // k-quarter, also epilogue row r
    const int r  = q;

    // one-time: W_h slice row (j0+j), quarter q -> 128 VGPRs
    float wreg[128];
    {
        const float* wp = &W_h[(size_t)(j0+j)*HID + q*128];
        #pragma unroll
        for (int n = 0; n < 32; n++) {
            float4 v = *(const float4*)&wp[n*4];
            wreg[4*n+0] = v.x; wreg[4*n+1] = v.y;
            wreg[4*n+2] = v.z; wreg[4*n+3] = v.w;
        }
    }
    const float bh = b_h[j0 + j];

    for (int s = 0; s < SEQ; s++) {
        // prefetch this step's proj (in act region) and noise early (HBM)
        const size_t eidx = ((size_t)(s*BATCH) + b0 + r)*HID + j0 + j;
        const float projv  = act[eidx];
        const float noisev = noise[eidx];

        if (s == 0) {
            #pragma unroll
            for (int n = 0; n < 8; n++) h_lds[n*256 + t] = 0.f;
            __syncthreads();
        } else {
            // wave 0: poll the 8 producer slots of step s-1 in parallel
            if (t < 64) {
                const int* sl = &slots[(((s-1)&1)*NGROUP + g)*NSLICE];
                bool ok;
                do {
                    ok = (t >= NSLICE) ||
                         (__hip_atomic_load(&sl[t], __ATOMIC_RELAXED,
                                            __HIP_MEMORY_SCOPE_AGENT) == s);
                } while (__ballot(ok) != 0xFFFFFFFFFFFFFFFFull);
            }
            __syncthreads();
            const float* hb = &h_buf[((s-1)&1)*(BATCH*HID) + (size_t)b0*HID];
            float hv[8];
            #pragma unroll
            for (int n = 0; n < 8; n++)
                hv[n] = __hip_atomic_load(&hb[n*256 + t], __ATOMIC_RELAXED,
                                          __HIP_MEMORY_SCOPE_AGENT);
            #pragma unroll
            for (int n = 0; n < 8; n++) h_lds[n*256 + t] = hv[n];
            __syncthreads();
        }

        // partial dot: acc[row] over k in [q*128, q*128+128)
        float a0 = 0.f, a1 = 0.f, a2 = 0.f, a3 = 0.f;
        const float* hq = &h_lds[q*128];
        #pragma unroll
        for (int kk = 0; kk < 128; kk += 4) {
            const float w0 = wreg[kk+0], w1 = wreg[kk+1];
            const float w2 = wreg[kk+2], w3 = wreg[kk+3];
            float4 h0v = *(const float4*)&hq[kk];
            float4 h1v = *(const float4*)&hq[kk + 512];
            float4 h2v = *(const float4*)&hq[kk + 1024];
            float4 h3v = *(const float4*)&hq[kk + 1536];
            a0 += w0*h0v.x + w1*h0v.y + w2*h0v.z + w3*h0v.w;
            a1 += w0*h1v.x + w1*h1v.y + w2*h1v.z + w3*h1v.w;
            a2 += w0*h2v.x + w1*h2v.y + w2*h2v.z + w3*h2v.w;
            a3 += w0*h3v.x + w1*h3v.y + w2*h3v.z + w3*h3v.w;
        }
        // [r][q][j] layout: conflict-free writes and reads
        part[0*256 + q*64 + j] = a0;
        part[1*256 + q*64 + j] = a1;
        part[2*256 + q*64 + j] = a2;
        part[3*256 + q*64 + j] = a3;
        __syncthreads();

        // reduce the 4 k-quarter partials for output (row r, col j0+j)
        float pre = part[r*256 + 0*64 + j] + part[r*256 + 1*64 + j]
                  + part[r*256 + 2*64 + j] + part[r*256 + 3*64 + j];
        pre += projv + bh + SIGMA_F * noisev;
        const float hprev = h_lds[r*512 + j0 + j];
        const float hn = OMA_F*hprev + AL_F*fmaxf(pre, 0.f);

        // publish h for peers (critical path)
        __hip_atomic_store(&h_buf[(s&1)*(BATCH*HID) + (size_t)(b0+r)*HID + j0 + j],
                           hn, __ATOMIC_RELAXED, __HIP_MEMORY_SCOPE_AGENT);
        __syncthreads();  // drains vmcnt: h stores committed at the LLC
        if (t == 0) {
            __hip_atomic_store(&slots[((s&1)*NGROUP + g)*NSLICE + p], s + 1,
                               __ATOMIC_RELAXED, __HIP_MEMORY_SCOPE_AGENT);
        }
        // activity write-back off the critical path (drains next iteration)
        act[eidx] = hn;
    }
}

// ---------------------------------------------------------------------------
// Phase 3: out[m,o] = sum_h act[m,h]*W_out[o,h] + b_out[o]
// (unchanged from previous round)
// ---------------------------------------------------------------------------
__global__ __launch_bounds__(256) void out_gemm_kernel(
    const float* __restrict__ act, const float* __restrict__ W_out,
    const float* __restrict__ b_out, float* __restrict__ out)
{
    __shared__ __align__(16) float xs[64*68];
    __shared__ __align__(16) float ws[64*70];
    const int m0 = blockIdx.x << 6;
    const int t  = threadIdx.x;
    const int tm = t >> 4, tn = t & 15;
    float acc[4][4] = {{0.f,0.f,0.f,0.f},{0.f,0.f,0.f,0.f},
                       {0.f,0.f,0.f,0.f},{0.f,0.f,0.f,0.f}};
    for (int kc = 0; kc < HID; kc += 64) {
        #pragma unroll
        for (int n = 0; n < 4; n++) {
            int f = n*256 + t;
            int row = f >> 4, c4 = (f & 15) << 2;
            *(float4*)&xs[row*68 + c4] =
                *(const float4*)&act[(size_t)(m0+row)*HID + kc + c4];
        }
        #pragma unroll
        for (int n = 0; n < 4; n++) {
            int f = n*256 + t;
            int row = f >> 4, c4 = (f & 15) << 2;
            float4 v = *(const float4*)&W_out[(size_t)row*HID + kc + c4];
            *(float2*)&ws[row*70 + c4]     = make_float2(v.x, v.y);
            *(float2*)&ws[row*70 + c4 + 2] = make_float2(v.z, v.w);
        }
        __syncthreads();
        #pragma unroll
        for (int k = 0; k < 64; k += 4) {
            float4 xv[4]; float4 wv[4];
            #pragma unroll
            for (int i = 0; i < 4; i++)
                xv[i] = *(const float4*)&xs[(tm*4+i)*68 + k];
            #pragma unroll
            for (int jj = 0; jj < 4; jj++) {
                float2 a = *(const float2*)&ws[(tn*4+jj)*70 + k];
                float2 b = *(const float2*)&ws[(tn*4+jj)*70 + k + 2];
                wv[jj] = make_float4(a.x, a.y, b.x, b.y);
            }
            #pragma unroll
            for (int i = 0; i < 4; i++)
                #pragma unroll
                for (int jj = 0; jj < 4; jj++)
                    acc[i][jj] += xv[i].x*wv[jj].x + xv[i].y*wv[jj].y
                                + xv[i].z*wv[jj].z + xv[i].w*wv[jj].w;
        }
        __syncthreads();
    }
    float4 bv = make_float4(b_out[tn*4+0], b_out[tn*4+1],
                            b_out[tn*4+2], b_out[tn*4+3]);
    #pragma unroll
    for (int i = 0; i < 4; i++) {
        float4 o = make_float4(acc[i][0]+bv.x, acc[i][1]+bv.y,
                               acc[i][2]+bv.z, acc[i][3]+bv.w);
        *(float4*)&out[(size_t)(m0+tm*4+i)*OUTP + tn*4] = o;
    }
}

// ---------------------------------------------------------------------------
extern "C" void kernel_launch(void* const* d_in, const int* in_sizes, int n_in,
                              void* d_out, int out_size, void* d_ws, size_t ws_size,
                              hipStream_t stream)
{
    const float* x     = (const float*)d_in[0];
    const float* noise = (const float*)d_in[1];
    const float* W_in  = (const float*)d_in[2];
    const float* b_in  = (const float*)d_in[3];
    const float* W_h   = (const float*)d_in[4];
    const float* b_h   = (const float*)d_in[5];
    const float* W_out = (const float*)d_in[6];
    const float* b_out = (const float*)d_in[7];

    float* out = (float*)d_out;
    float* act = out + (size_t)M1*OUTP;          // rnn_activity region

    int*   slots = (int*)d_ws;                   // [2][NGROUP][NSLICE] ints
    float* h_buf = (float*)((char*)d_ws + 2*NGROUP*NSLICE*sizeof(int));

    hipMemsetAsync(slots, 0, 2*NGROUP*NSLICE*sizeof(int), stream);

    proj_gemm_kernel<<<dim3((M1/64)*(HID/64)), dim3(256), 0, stream>>>(
        x, W_in, b_in, act);
    scan_kernel<<<dim3(NGROUP*NSLICE), dim3(256), 0, stream>>>(
        noise, W_h, b_h, act, h_buf, slots);
    out_gemm_kernel<<<dim3(M1/64), dim3(256), 0, stream>>>(
        act, W_out, b_out, out);
}

// Round 2
// 5348.589 us; speedup vs baseline: 1.4681x; 1.0679x over previous
//
#include <hip/hip_runtime.h>
#include <cstdint>

#define SEQ   1024
#define BATCH 128
#define INP   128
#define HID   512
#define OUTP  64
#define M1    (SEQ*BATCH)          // 131072

#define OMA_F   0.8f               // 1 - alpha
#define AL_F    0.2f               // alpha
#define SIGMA_F 0.031622776601683794f  // sqrt(2*0.2)*0.05

#define NGROUP  32                 // batch groups (4 rows each)
#define NSLICE  8                  // j-slices per group (64 j each)

// ---------------------------------------------------------------------------
// Phase 1: inp[s,b,h] = sum_i x[s,b,i]*W_in[h,i] + b_in[h] + b_h[h]
//                       + SIGMA*noise[s,b,h]
// All per-step additive terms folded in, so the scan reads ONE stream.
// Written into the rnn_activity region of d_out (scan overwrites in place).
// ---------------------------------------------------------------------------
__global__ __launch_bounds__(256) void proj_gemm_kernel(
    const float* __restrict__ x, const float* __restrict__ W_in,
    const float* __restrict__ b_in, const float* __restrict__ b_h,
    const float* __restrict__ noise, float* __restrict__ act)
{
    __shared__ __align__(16) float xs[64*68];
    __shared__ __align__(16) float ws[64*70];
    const int bid = blockIdx.x;
    const int mt = bid >> 3, nt = bid & 7;
    const int m0 = mt << 6, n0 = nt << 6;
    const int t  = threadIdx.x;
    const int tm = t >> 4, tn = t & 15;
    float acc[4][4] = {{0.f,0.f,0.f,0.f},{0.f,0.f,0.f,0.f},
                       {0.f,0.f,0.f,0.f},{0.f,0.f,0.f,0.f}};
    for (int kc = 0; kc < INP; kc += 64) {
        #pragma unroll
        for (int n = 0; n < 4; n++) {
            int f = n*256 + t;
            int row = f >> 4, c4 = (f & 15) << 2;
            float4 v = *(const float4*)&x[(size_t)(m0+row)*INP + kc + c4];
            *(float4*)&xs[row*68 + c4] = v;
        }
        #pragma unroll
        for (int n = 0; n < 4; n++) {
            int f = n*256 + t;
            int row = f >> 4, c4 = (f & 15) << 2;
            float4 v = *(const float4*)&W_in[(size_t)(n0+row)*INP + kc + c4];
            *(float2*)&ws[row*70 + c4]     = make_float2(v.x, v.y);
            *(float2*)&ws[row*70 + c4 + 2] = make_float2(v.z, v.w);
        }
        __syncthreads();
        #pragma unroll
        for (int k = 0; k < 64; k += 4) {
            float4 xv[4]; float4 wv[4];
            #pragma unroll
            for (int i = 0; i < 4; i++)
                xv[i] = *(const float4*)&xs[(tm*4+i)*68 + k];
            #pragma unroll
            for (int jj = 0; jj < 4; jj++) {
                float2 a = *(const float2*)&ws[(tn*4+jj)*70 + k];
                float2 b = *(const float2*)&ws[(tn*4+jj)*70 + k + 2];
                wv[jj] = make_float4(a.x, a.y, b.x, b.y);
            }
            #pragma unroll
            for (int i = 0; i < 4; i++)
                #pragma unroll
                for (int jj = 0; jj < 4; jj++)
                    acc[i][jj] += xv[i].x*wv[jj].x + xv[i].y*wv[jj].y
                                + xv[i].z*wv[jj].z + xv[i].w*wv[jj].w;
        }
        __syncthreads();
    }
    float4 bv = make_float4(b_in[n0+tn*4+0] + b_h[n0+tn*4+0],
                            b_in[n0+tn*4+1] + b_h[n0+tn*4+1],
                            b_in[n0+tn*4+2] + b_h[n0+tn*4+2],
                            b_in[n0+tn*4+3] + b_h[n0+tn*4+3]);
    #pragma unroll
    for (int i = 0; i < 4; i++) {
        const size_t rowb = (size_t)(m0+tm*4+i)*HID + n0 + tn*4;
        float4 nv = *(const float4*)&noise[rowb];
        float4 o = make_float4(acc[i][0]+bv.x + SIGMA_F*nv.x,
                               acc[i][1]+bv.y + SIGMA_F*nv.y,
                               acc[i][2]+bv.z + SIGMA_F*nv.z,
                               acc[i][3]+bv.w + SIGMA_F*nv.w);
        *(float4*)&act[rowb] = o;
    }
}

// ---------------------------------------------------------------------------
// Phase 2: sequential scan.
// 256 blocks = 32 groups (4 batch rows) x 8 slices (64 hidden j's).
// Handshake v3 — TAG-IN-DATA:
//  - h is published as one aligned 8-byte word per element:
//      {low32 = f32 h value, high32 = u32 tag = s+1}
//    via a single relaxed agent-scope dwordx2 store. The store IS the
//    publication: no separate flag, no pre-flag vmcnt drain on the
//    critical path, no separate data load after the poll.
//  - each consumer thread polls its OWN 8 entries (tag == s); when the
//    tag matches, the value arrived in the same atomic 8-byte load.
//  - ABA-safe: a producer reaches its parity-slot overwrite at step s+2
//    only after observing every peer's (s+1)-tag, which requires every
//    peer (every poller of this slot) to have passed its s-poll; and
//    tag+data are one atomic load, so a fresh tag implies fresh data.
// ---------------------------------------------------------------------------
__global__ __launch_bounds__(256, 1) void scan_kernel(
    const float* __restrict__ W_h, float* __restrict__ act,
    unsigned long long* h_buf2)
{
    __shared__ __align__(16) float h_lds[4*512];   // 4 rows x 512
    __shared__ __align__(16) float part[4*4*64];   // [r][q][j]
    const int bid = blockIdx.x;
    const int g  = bid & (NGROUP-1);      // group: rows b0..b0+3
    const int p  = bid >> 5;              // slice: j0..j0+63
    const int b0 = g << 2;
    const int j0 = p << 6;
    const int t  = threadIdx.x;
    const int j  = t & 63;
    const int q  = t >> 6;                // k-quarter, also epilogue row r
    const int r  = q;

    // one-time: W_h slice row (j0+j), quarter q -> 128 VGPRs
    float wreg[128];
    {
        const float* wp = &W_h[(size_t)(j0+j)*HID + q*128];
        #pragma unroll
        for (int n = 0; n < 32; n++) {
            float4 v = *(const float4*)&wp[n*4];
            wreg[4*n+0] = v.x; wreg[4*n+1] = v.y;
            wreg[4*n+2] = v.z; wreg[4*n+3] = v.w;
        }
    }

    for (int s = 0; s < SEQ; s++) {
        // prefetch this step's combined input (proj+b_in+b_h+sigma*noise)
        const size_t eidx = ((size_t)(s*BATCH) + b0 + r)*HID + j0 + j;
        const float inpv = act[eidx];

        if (s == 0) {
            #pragma unroll
            for (int n = 0; n < 8; n++) h_lds[n*256 + t] = 0.f;
            __syncthreads();
        } else {
            // poll own 8 tagged entries of step s-1 (tag == s)
            const unsigned long long* hb =
                &h_buf2[(size_t)((s-1)&1)*(BATCH*HID) + (size_t)b0*HID];
            unsigned long long v[8];
            #pragma unroll
            for (int n = 0; n < 8; n++)
                v[n] = __hip_atomic_load(&hb[n*256 + t], __ATOMIC_RELAXED,
                                         __HIP_MEMORY_SCOPE_AGENT);
            while (true) {
                unsigned bad = 0;
                #pragma unroll
                for (int n = 0; n < 8; n++)
                    if ((unsigned)(v[n] >> 32) != (unsigned)s) bad |= 1u << n;
                if (!bad) break;
                #pragma unroll
                for (int n = 0; n < 8; n++)
                    if (bad & (1u << n))
                        v[n] = __hip_atomic_load(&hb[n*256 + t],
                                                 __ATOMIC_RELAXED,
                                                 __HIP_MEMORY_SCOPE_AGENT);
            }
            __syncthreads();   // A: previous step's h_lds/part readers done
            #pragma unroll
            for (int n = 0; n < 8; n++)
                h_lds[n*256 + t] = __uint_as_float((unsigned)v[n]);
            __syncthreads();   // B: h_lds filled
        }

        // partial dot: acc[row] over k in [q*128, q*128+128)
        float a0 = 0.f, a1 = 0.f, a2 = 0.f, a3 = 0.f;
        const float* hq = &h_lds[q*128];
        #pragma unroll
        for (int kk = 0; kk < 128; kk += 4) {
            const float w0 = wreg[kk+0], w1 = wreg[kk+1];
            const float w2 = wreg[kk+2], w3 = wreg[kk+3];
            float4 h0v = *(const float4*)&hq[kk];
            float4 h1v = *(const float4*)&hq[kk + 512];
            float4 h2v = *(const float4*)&hq[kk + 1024];
            float4 h3v = *(const float4*)&hq[kk + 1536];
            a0 += w0*h0v.x + w1*h0v.y + w2*h0v.z + w3*h0v.w;
            a1 += w0*h1v.x + w1*h1v.y + w2*h1v.z + w3*h1v.w;
            a2 += w0*h2v.x + w1*h2v.y + w2*h2v.z + w3*h2v.w;
            a3 += w0*h3v.x + w1*h3v.y + w2*h3v.z + w3*h3v.w;
        }
        // [r][q][j] layout: conflict-free writes and reads
        part[0*256 + q*64 + j] = a0;
        part[1*256 + q*64 + j] = a1;
        part[2*256 + q*64 + j] = a2;
        part[3*256 + q*64 + j] = a3;
        __syncthreads();       // C

        // reduce the 4 k-quarter partials for output (row r, col j0+j)
        float pre = part[r*256 + 0*64 + j] + part[r*256 + 1*64 + j]
                  + part[r*256 + 2*64 + j] + part[r*256 + 3*64 + j];
        pre += inpv;
        const float hprev = h_lds[r*512 + j0 + j];
        const float hn = OMA_F*hprev + AL_F*fmaxf(pre, 0.f);

        // publish h+tag in ONE atomic 8-byte store (the critical path)
        const unsigned long long pk =
            ((unsigned long long)(unsigned)(s + 1) << 32) | __float_as_uint(hn);
        __hip_atomic_store(
            &h_buf2[(size_t)(s&1)*(BATCH*HID) + (size_t)(b0+r)*HID + j0 + j],
            pk, __ATOMIC_RELAXED, __HIP_MEMORY_SCOPE_AGENT);

        // activity write-back off the critical path (drains during next poll)
        act[eidx] = hn;
    }
}

// ---------------------------------------------------------------------------
// Phase 3: out[m,o] = sum_h act[m,h]*W_out[o,h] + b_out[o]
// (unchanged)
// ---------------------------------------------------------------------------
__global__ __launch_bounds__(256) void out_gemm_kernel(
    const float* __restrict__ act, const float* __restrict__ W_out,
    const float* __restrict__ b_out, float* __restrict__ out)
{
    __shared__ __align__(16) float xs[64*68];
    __shared__ __align__(16) float ws[64*70];
    const int m0 = blockIdx.x << 6;
    const int t  = threadIdx.x;
    const int tm = t >> 4, tn = t & 15;
    float acc[4][4] = {{0.f,0.f,0.f,0.f},{0.f,0.f,0.f,0.f},
                       {0.f,0.f,0.f,0.f},{0.f,0.f,0.f,0.f}};
    for (int kc = 0; kc < HID; kc += 64) {
        #pragma unroll
        for (int n = 0; n < 4; n++) {
            int f = n*256 + t;
            int row = f >> 4, c4 = (f & 15) << 2;
            *(float4*)&xs[row*68 + c4] =
                *(const float4*)&act[(size_t)(m0+row)*HID + kc + c4];
        }
        #pragma unroll
        for (int n = 0; n < 4; n++) {
            int f = n*256 + t;
            int row = f >> 4, c4 = (f & 15) << 2;
            float4 v = *(const float4*)&W_out[(size_t)row*HID + kc + c4];
            *(float2*)&ws[row*70 + c4]     = make_float2(v.x, v.y);
            *(float2*)&ws[row*70 + c4 + 2] = make_float2(v.z, v.w);
        }
        __syncthreads();
        #pragma unroll
        for (int k = 0; k < 64; k += 4) {
            float4 xv[4]; float4 wv[4];
            #pragma unroll
            for (int i = 0; i < 4; i++)
                xv[i] = *(const float4*)&xs[(tm*4+i)*68 + k];
            #pragma unroll
            for (int jj = 0; jj < 4; jj++) {
                float2 a = *(const float2*)&ws[(tn*4+jj)*70 + k];
                float2 b = *(const float2*)&ws[(tn*4+jj)*70 + k + 2];
                wv[jj] = make_float4(a.x, a.y, b.x, b.y);
            }
            #pragma unroll
            for (int i = 0; i < 4; i++)
                #pragma unroll
                for (int jj = 0; jj < 4; jj++)
                    acc[i][jj] += xv[i].x*wv[jj].x + xv[i].y*wv[jj].y
                                + xv[i].z*wv[jj].z + xv[i].w*wv[jj].w;
        }
        __syncthreads();
    }
    float4 bv = make_float4(b_out[tn*4+0], b_out[tn*4+1],
                            b_out[tn*4+2], b_out[tn*4+3]);
    #pragma unroll
    for (int i = 0; i < 4; i++) {
        float4 o = make_float4(acc[i][0]+bv.x, acc[i][1]+bv.y,
                               acc[i][2]+bv.z, acc[i][3]+bv.w);
        *(float4*)&out[(size_t)(m0+tm*4+i)*OUTP + tn*4] = o;
    }
}

// ---------------------------------------------------------------------------
extern "C" void kernel_launch(void* const* d_in, const int* in_sizes, int n_in,
                              void* d_out, int out_size, void* d_ws, size_t ws_size,
                              hipStream_t stream)
{
    const float* x     = (const float*)d_in[0];
    const float* noise = (const float*)d_in[1];
    const float* W_in  = (const float*)d_in[2];
    const float* b_in  = (const float*)d_in[3];
    const float* W_h   = (const float*)d_in[4];
    const float* b_h   = (const float*)d_in[5];
    const float* W_out = (const float*)d_in[6];
    const float* b_out = (const float*)d_in[7];

    float* out = (float*)d_out;
    float* act = out + (size_t)M1*OUTP;          // rnn_activity region

    unsigned long long* h_buf2 = (unsigned long long*)d_ws; // 2*128*512 u64 = 1MB

    hipMemsetAsync(h_buf2, 0, (size_t)2*BATCH*HID*sizeof(unsigned long long),
                   stream);

    proj_gemm_kernel<<<dim3((M1/64)*(HID/64)), dim3(256), 0, stream>>>(
        x, W_in, b_in, b_h, noise, act);
    scan_kernel<<<dim3(NGROUP*NSLICE), dim3(256), 0, stream>>>(
        W_h, act, h_buf2);
    out_gemm_kernel<<<dim3(M1/64), dim3(256), 0, stream>>>(
        act, W_out, b_out, out);
}

// Round 3
// 3698.628 us; speedup vs baseline: 2.1230x; 1.4461x over previous
//
#include <hip/hip_runtime.h>
#include <cstdint>

#define SEQ   1024
#define BATCH 128
#define INP   128
#define HID   512
#define OUTP  64
#define M1    (SEQ*BATCH)          // 131072

#define OMA_F   0.8f               // 1 - alpha
#define AL_F    0.2f               // alpha
#define SIGMA_F 0.031622776601683794f  // sqrt(2*0.2)*0.05

#define NGROUP  64                 // batch groups (2 rows each)
#define NSLICE  4                  // j-slices per group (128 j each)
#define SBATCH  4                  // act write-back batching (steps)

#define AL(p) __hip_atomic_load((p), __ATOMIC_RELAXED, __HIP_MEMORY_SCOPE_AGENT)

// ---------------------------------------------------------------------------
// Phase 1: inp[s,b,h] = sum_i x[s,b,i]*W_in[h,i] + b_in[h] + b_h[h]
//                       + SIGMA*noise[s,b,h]   (unchanged)
// ---------------------------------------------------------------------------
__global__ __launch_bounds__(256) void proj_gemm_kernel(
    const float* __restrict__ x, const float* __restrict__ W_in,
    const float* __restrict__ b_in, const float* __restrict__ b_h,
    const float* __restrict__ noise, float* __restrict__ act)
{
    __shared__ __align__(16) float xs[64*68];
    __shared__ __align__(16) float ws[64*70];
    const int bid = blockIdx.x;
    const int mt = bid >> 3, nt = bid & 7;
    const int m0 = mt << 6, n0 = nt << 6;
    const int t  = threadIdx.x;
    const int tm = t >> 4, tn = t & 15;
    float acc[4][4] = {{0.f,0.f,0.f,0.f},{0.f,0.f,0.f,0.f},
                       {0.f,0.f,0.f,0.f},{0.f,0.f,0.f,0.f}};
    for (int kc = 0; kc < INP; kc += 64) {
        #pragma unroll
        for (int n = 0; n < 4; n++) {
            int f = n*256 + t;
            int row = f >> 4, c4 = (f & 15) << 2;
            float4 v = *(const float4*)&x[(size_t)(m0+row)*INP + kc + c4];
            *(float4*)&xs[row*68 + c4] = v;
        }
        #pragma unroll
        for (int n = 0; n < 4; n++) {
            int f = n*256 + t;
            int row = f >> 4, c4 = (f & 15) << 2;
            float4 v = *(const float4*)&W_in[(size_t)(n0+row)*INP + kc + c4];
            *(float2*)&ws[row*70 + c4]     = make_float2(v.x, v.y);
            *(float2*)&ws[row*70 + c4 + 2] = make_float2(v.z, v.w);
        }
        __syncthreads();
        #pragma unroll
        for (int k = 0; k < 64; k += 4) {
            float4 xv[4]; float4 wv[4];
            #pragma unroll
            for (int i = 0; i < 4; i++)
                xv[i] = *(const float4*)&xs[(tm*4+i)*68 + k];
            #pragma unroll
            for (int jj = 0; jj < 4; jj++) {
                float2 a = *(const float2*)&ws[(tn*4+jj)*70 + k];
                float2 b = *(const float2*)&ws[(tn*4+jj)*70 + k + 2];
                wv[jj] = make_float4(a.x, a.y, b.x, b.y);
            }
            #pragma unroll
            for (int i = 0; i < 4; i++)
                #pragma unroll
                for (int jj = 0; jj < 4; jj++)
                    acc[i][jj] += xv[i].x*wv[jj].x + xv[i].y*wv[jj].y
                                + xv[i].z*wv[jj].z + xv[i].w*wv[jj].w;
        }
        __syncthreads();
    }
    float4 bv = make_float4(b_in[n0+tn*4+0] + b_h[n0+tn*4+0],
                            b_in[n0+tn*4+1] + b_h[n0+tn*4+1],
                            b_in[n0+tn*4+2] + b_h[n0+tn*4+2],
                            b_in[n0+tn*4+3] + b_h[n0+tn*4+3]);
    #pragma unroll
    for (int i = 0; i < 4; i++) {
        const size_t rowb = (size_t)(m0+tm*4+i)*HID + n0 + tn*4;
        float4 nv = *(const float4*)&noise[rowb];
        float4 o = make_float4(acc[i][0]+bv.x + SIGMA_F*nv.x,
                               acc[i][1]+bv.y + SIGMA_F*nv.y,
                               acc[i][2]+bv.z + SIGMA_F*nv.z,
                               acc[i][3]+bv.w + SIGMA_F*nv.w);
        *(float4*)&act[rowb] = o;
    }
}

// ---------------------------------------------------------------------------
// Phase 2: sequential scan — v4.
// 256 blocks = 64 groups (2 batch rows) x 4 slices (128 j's). 512 threads.
//  - rows-per-group halved 4->2: per-CU broadcast ds_read_b128 per step
//    drops 512->256 (the LDS return bus was the co-dominant cost).
//  - k split 8-way across waves; wave w polls exactly ONE producer block
//    (slice w/2) and fills ONLY its own h_lds region -> no fill barriers,
//    per-wave jitter absorption. ABA-safe: each block's waves collectively
//    poll all 4 peer blocks, so a block's step-s publish certifies all its
//    waves finished step s-1; overwrite at s+2 therefore cannot race
//    readers of s+1.
//  - tag-in-data publish (8B atomic {f32,tag}) kept from v3.
//  - act write-back batched SBATCH steps in VGPRs (compile-time index via
//    unrolled sub-loop): HBM store ack leaves the per-step vmcnt chain.
//  - 2 barriers/step (part write->read, read->next write), both issued at
//    points with no heavy outstanding vmem -> no store-drain stalls.
// ---------------------------------------------------------------------------
__global__ __launch_bounds__(512, 2) void scan_kernel(
    const float* __restrict__ W_h, float* __restrict__ act,
    unsigned long long* h_buf2)
{
    __shared__ __align__(16) float h_lds[8*128];    // [wave][rr*64 + kk]
    __shared__ __align__(16) float part[2*8*128];   // [rr][wave][j]
    const int bid = blockIdx.x;
    const int g  = bid & (NGROUP-1);      // group: rows b0..b0+1
    const int p  = bid >> 6;              // slice: j0..j0+127
    const int b0 = g << 1;
    const int j0 = p << 7;
    const int t  = threadIdx.x;
    const int w  = t >> 6;                // wave 0..7 : k in [64w, 64w+64)
    const int l  = t & 63;

    // W_h: thread holds j in {j0+l, j0+64+l}, k in [64w, 64w+64) -> 128 VGPR
    float wreg0[64], wreg1[64];
    {
        const float* wp0 = &W_h[(size_t)(j0 + l)*HID + (w<<6)];
        const float* wp1 = &W_h[(size_t)(j0 + 64 + l)*HID + (w<<6)];
        #pragma unroll
        for (int n = 0; n < 16; n++) {
            float4 a = *(const float4*)&wp0[n*4];
            wreg0[4*n+0]=a.x; wreg0[4*n+1]=a.y; wreg0[4*n+2]=a.z; wreg0[4*n+3]=a.w;
            float4 b = *(const float4*)&wp1[n*4];
            wreg1[4*n+0]=b.x; wreg1[4*n+1]=b.y; wreg1[4*n+2]=b.z; wreg1[4*n+3]=b.w;
        }
    }

    // epilogue role: threads t<256: rr = t>>7, j = t&127 (one output each)
    const int  err = t >> 7, ej = t & 127;
    const bool epi = (t < 256);
    float hprev = 0.f;
    float acth[SBATCH];
    float inpv = 0.f;
    if (epi) inpv = act[(size_t)(b0 + err)*HID + j0 + ej];   // s=0 prefetch

    for (int s8 = 0; s8 < SEQ; s8 += SBATCH) {
        #pragma unroll
        for (int u = 0; u < SBATCH; u++) {
            const int s = s8 + u;
            if (s == 0) {
                h_lds[(w<<7) + l]      = 0.f;
                h_lds[(w<<7) + 64 + l] = 0.f;
            } else {
                // wave-local poll of ONE producer (slice w/2), 2 entries/lane
                const unsigned long long* hb =
                    &h_buf2[(size_t)((s-1)&1)*(BATCH*HID)];
                const unsigned long long* e0 = &hb[(size_t)b0*HID + (w<<6) + l];
                const unsigned long long* e1 = e0 + HID;
                unsigned long long v0 = AL(e0), v1 = AL(e1);
                while (((unsigned)(v0>>32) != (unsigned)s) |
                       ((unsigned)(v1>>32) != (unsigned)s)) {
                    if ((unsigned)(v0>>32) != (unsigned)s) v0 = AL(e0);
                    if ((unsigned)(v1>>32) != (unsigned)s) v1 = AL(e1);
                }
                h_lds[(w<<7) + l]      = __uint_as_float((unsigned)v0);
                h_lds[(w<<7) + 64 + l] = __uint_as_float((unsigned)v1);
            }
            // wave-local fill->read: in-wave lgkmcnt ordering, no barrier

            float a00=0.f, a01=0.f, a10=0.f, a11=0.f;   // [rr][jj]
            {
                const float* h0 = &h_lds[w<<7];
                #pragma unroll
                for (int kk = 0; kk < 64; kk += 4) {
                    float4 hv0 = *(const float4*)&h0[kk];
                    float4 hv1 = *(const float4*)&h0[64 + kk];
                    a00 += wreg0[kk]*hv0.x + wreg0[kk+1]*hv0.y
                         + wreg0[kk+2]*hv0.z + wreg0[kk+3]*hv0.w;
                    a01 += wreg1[kk]*hv0.x + wreg1[kk+1]*hv0.y
                         + wreg1[kk+2]*hv0.z + wreg1[kk+3]*hv0.w;
                    a10 += wreg0[kk]*hv1.x + wreg0[kk+1]*hv1.y
                         + wreg0[kk+2]*hv1.z + wreg0[kk+3]*hv1.w;
                    a11 += wreg1[kk]*hv1.x + wreg1[kk+1]*hv1.y
                         + wreg1[kk+2]*hv1.z + wreg1[kk+3]*hv1.w;
                }
            }
            part[(0*8 + w)*128 + l]      = a00;
            part[(0*8 + w)*128 + 64 + l] = a01;
            part[(1*8 + w)*128 + l]      = a10;
            part[(1*8 + w)*128 + 64 + l] = a11;
            __syncthreads();   // C: partials ready

            float hn = 0.f;
            if (epi) {
                const float* pr = &part[err*8*128 + ej];
                float pre = pr[0] + pr[128] + pr[256] + pr[384]
                          + pr[512] + pr[640] + pr[768] + pr[896];
                pre += inpv;
                hn = OMA_F*hprev + AL_F*fmaxf(pre, 0.f);
                hprev = hn;
                acth[u] = hn;
            }
            __syncthreads();   // A': part reads done; next writes safe

            if (epi) {
                const unsigned long long pk =
                    ((unsigned long long)(unsigned)(s + 1) << 32)
                    | __float_as_uint(hn);
                __hip_atomic_store(
                    &h_buf2[(size_t)(s&1)*(BATCH*HID)
                            + (size_t)(b0+err)*HID + j0 + ej],
                    pk, __ATOMIC_RELAXED, __HIP_MEMORY_SCOPE_AGENT);
                if (u == SBATCH-1) {
                    #pragma unroll
                    for (int uu = 0; uu < SBATCH; uu++)
                        act[((size_t)((s8+uu)*BATCH) + b0 + err)*HID + j0 + ej]
                            = acth[uu];
                }
                const int sn = (s+1 < SEQ) ? s+1 : s;
                inpv = act[((size_t)(sn*BATCH) + b0 + err)*HID + j0 + ej];
            }
        }
    }
}

// ---------------------------------------------------------------------------
// Phase 3: out[m,o] = sum_h act[m,h]*W_out[o,h] + b_out[o]   (unchanged)
// ---------------------------------------------------------------------------
__global__ __launch_bounds__(256) void out_gemm_kernel(
    const float* __restrict__ act, const float* __restrict__ W_out,
    const float* __restrict__ b_out, float* __restrict__ out)
{
    __shared__ __align__(16) float xs[64*68];
    __shared__ __align__(16) float ws[64*70];
    const int m0 = blockIdx.x << 6;
    const int t  = threadIdx.x;
    const int tm = t >> 4, tn = t & 15;
    float acc[4][4] = {{0.f,0.f,0.f,0.f},{0.f,0.f,0.f,0.f},
                       {0.f,0.f,0.f,0.f},{0.f,0.f,0.f,0.f}};
    for (int kc = 0; kc < HID; kc += 64) {
        #pragma unroll
        for (int n = 0; n < 4; n++) {
            int f = n*256 + t;
            int row = f >> 4, c4 = (f & 15) << 2;
            *(float4*)&xs[row*68 + c4] =
                *(const float4*)&act[(size_t)(m0+row)*HID + kc + c4];
        }
        #pragma unroll
        for (int n = 0; n < 4; n++) {
            int f = n*256 + t;
            int row = f >> 4, c4 = (f & 15) << 2;
            float4 v = *(const float4*)&W_out[(size_t)row*HID + kc + c4];
            *(float2*)&ws[row*70 + c4]     = make_float2(v.x, v.y);
            *(float2*)&ws[row*70 + c4 + 2] = make_float2(v.z, v.w);
        }
        __syncthreads();
        #pragma unroll
        for (int k = 0; k < 64; k += 4) {
            float4 xv[4]; float4 wv[4];
            #pragma unroll
            for (int i = 0; i < 4; i++)
                xv[i] = *(const float4*)&xs[(tm*4+i)*68 + k];
            #pragma unroll
            for (int jj = 0; jj < 4; jj++) {
                float2 a = *(const float2*)&ws[(tn*4+jj)*70 + k];
                float2 b = *(const float2*)&ws[(tn*4+jj)*70 + k + 2];
                wv[jj] = make_float4(a.x, a.y, b.x, b.y);
            }
            #pragma unroll
            for (int i = 0; i < 4; i++)
                #pragma unroll
                for (int jj = 0; jj < 4; jj++)
                    acc[i][jj] += xv[i].x*wv[jj].x + xv[i].y*wv[jj].y
                                + xv[i].z*wv[jj].z + xv[i].w*wv[jj].w;
        }
        __syncthreads();
    }
    float4 bv = make_float4(b_out[tn*4+0], b_out[tn*4+1],
                            b_out[tn*4+2], b_out[tn*4+3]);
    #pragma unroll
    for (int i = 0; i < 4; i++) {
        float4 o = make_float4(acc[i][0]+bv.x, acc[i][1]+bv.y,
                               acc[i][2]+bv.z, acc[i][3]+bv.w);
        *(float4*)&out[(size_t)(m0+tm*4+i)*OUTP + tn*4] = o;
    }
}

// ---------------------------------------------------------------------------
extern "C" void kernel_launch(void* const* d_in, const int* in_sizes, int n_in,
                              void* d_out, int out_size, void* d_ws, size_t ws_size,
                              hipStream_t stream)
{
    const float* x     = (const float*)d_in[0];
    const float* noise = (const float*)d_in[1];
    const float* W_in  = (const float*)d_in[2];
    const float* b_in  = (const float*)d_in[3];
    const float* W_h   = (const float*)d_in[4];
    const float* b_h   = (const float*)d_in[5];
    const float* W_out = (const float*)d_in[6];
    const float* b_out = (const float*)d_in[7];

    float* out = (float*)d_out;
    float* act = out + (size_t)M1*OUTP;          // rnn_activity region

    unsigned long long* h_buf2 = (unsigned long long*)d_ws; // 2*128*512 u64 = 1MB

    hipMemsetAsync(h_buf2, 0, (size_t)2*BATCH*HID*sizeof(unsigned long long),
                   stream);

    proj_gemm_kernel<<<dim3((M1/64)*(HID/64)), dim3(256), 0, stream>>>(
        x, W_in, b_in, b_h, noise, act);
    scan_kernel<<<dim3(NGROUP*NSLICE), dim3(512), 0, stream>>>(
        W_h, act, h_buf2);
    out_gemm_kernel<<<dim3(M1/64), dim3(256), 0, stream>>>(
        act, W_out, b_out, out);
}